// Round 1
// baseline (276.269 us; speedup 1.0000x reference)
//
#include <hip/hip_runtime.h>
#include <hip/hip_bf16.h>
#include <math.h>
#include <stdint.h>

// ArcFace loss via MX-fp8 (e4m3, identity scales) MFMA GEMM + fused
// fixed-max softmax. B=2048, D=512, C=50000. Output: scalar mean NLL (f32).
//
// R6: latency-fix for the non-GEMM kernels (k_gemm untouched as control).
//  - k_prep: 4 rows/wave, all 8 float4 loads issued up-front (128 B/lane in
//    flight vs 32 B). Old version was latency-bound at ~1.2 TB/s (one 2KB row
//    per wave, 2 loads outstanding); new version should be HBM-bound (~25 us).
//  - k_fin: 2 waves/row (role 0: exact label dot; role 1: partial-sum with 7
//    predicated loads issued together). Same per-row fp ordering as before.
//
// Numerics: logits = 30*cos in [-30,30] -> fixed max 30, plain sums:
//   lse = 30 + log(sum_c exp(l_c - 30)); label logit recomputed exactly in
//   fp32 at finalize, so fp8 error only perturbs the softmax denominator.

#define B_ROWS    2048
#define D_DIM     512
#define C_CLASSES 50000
#define C_PAD     50048            // 391 * 128
#define NCHUNK    391
#define CPX       49               // chunks per XCD (8*49=392 slots, 1 unused)
#define ARC_MARGIN 0.3f
#define ARC_SCALE  30.0f
#define ARC_EPS    1e-12f
#define K_LOG2E_S  43.2808512f     // 30 * log2(e)

// workspace layout (bytes)
#define OFF_WQ    0u               // 50048*512 = 25,624,576
#define OFF_EMBQ  25624576u        // 2048*512  =  1,048,576
#define OFF_WINV  26673152u        // 50000*4   =    200,000
#define OFF_EINV  26873152u        // 2048*4    =      8,192
#define OFF_PART  26881344u        // 2048*391*4 = 3,203,072
// total ~30.1 MB

typedef __attribute__((ext_vector_type(8))) int   i32x8;
typedef __attribute__((ext_vector_type(4))) int   i32x4;
typedef __attribute__((ext_vector_type(4))) float f32x4;

typedef __attribute__((address_space(1))) const unsigned int g_u32;
typedef __attribute__((address_space(3))) unsigned int       l_u32;

__device__ __forceinline__ void gload_lds16(const void* g, void* l) {
    // dest is wave-uniform LDS base; HW writes lane i at base + i*16
    g_u32* gp = (g_u32*)(uintptr_t)g;
    l_u32* lp = (l_u32*)(uintptr_t)l;
    __builtin_amdgcn_global_load_lds(gp, lp, 16, 0, 0);
}

// ---------------- prep: rows -> normalized e4m3 + inverse norms ----------------
// One wave per 4 consecutive rows. Row space: [0,C_PAD) = weight (pad rows
// zero-filled), [C_PAD, C_PAD+B) = embeddings. All three segments are
// multiples of 4 rows, so a 4-row group never straddles segments.
__global__ __launch_bounds__(256) void k_prep(const float* __restrict__ emb,
                                              const float* __restrict__ weight,
                                              uint8_t* __restrict__ embq,
                                              uint8_t* __restrict__ wq,
                                              float* __restrict__ einv,
                                              float* __restrict__ winv,
                                              float* __restrict__ out) {
    if (blockIdx.x == 0 && threadIdx.x == 0) out[0] = 0.f;  // zero for k_fin atomics
    int wave = blockIdx.x * (blockDim.x >> 6) + (threadIdx.x >> 6);
    int lane = threadIdx.x & 63;
    int g0   = wave << 2;              // first of 4 consecutive rows

    const float* src;
    uint8_t* dst;
    float* invout;
    if (g0 >= C_PAD) {                 // embedding rows
        int row = g0 - C_PAD;
        src = emb + (size_t)row * D_DIM;
        dst = embq + (size_t)row * D_DIM;
        invout = einv + row;
    } else if (g0 >= C_CLASSES) {      // zero-fill pad classes
        int2 z = make_int2(0, 0);
        #pragma unroll
        for (int r = 0; r < 4; ++r)
            *(int2*)(wq + (size_t)(g0 + r) * D_DIM + lane * 8) = z;
        return;
    } else {                           // weight rows
        src = weight + (size_t)g0 * D_DIM;
        dst = wq + (size_t)g0 * D_DIM;
        invout = winv + g0;
    }

    // issue all 8 loads before any use: 128 B/lane outstanding
    const float4* r4 = (const float4*)src;
    float4 v[8];
    #pragma unroll
    for (int r = 0; r < 4; ++r) {
        v[2 * r]     = r4[r * 128 + lane * 2];
        v[2 * r + 1] = r4[r * 128 + lane * 2 + 1];
    }

    #pragma unroll
    for (int r = 0; r < 4; ++r) {
        float4 v0 = v[2 * r], v1 = v[2 * r + 1];
        float s = v0.x*v0.x + v0.y*v0.y + v0.z*v0.z + v0.w*v0.w
                + v1.x*v1.x + v1.y*v1.y + v1.z*v1.z + v1.w*v1.w;
        #pragma unroll
        for (int off = 32; off; off >>= 1) s += __shfl_xor(s, off);
        float rn = 1.0f / fmaxf(sqrtf(s), ARC_EPS);
        if (lane == 0) invout[r] = rn;
        int p0 = __builtin_amdgcn_cvt_pk_fp8_f32(v0.x * rn, v0.y * rn, 0, false);
        p0     = __builtin_amdgcn_cvt_pk_fp8_f32(v0.z * rn, v0.w * rn, p0, true);
        int p1 = __builtin_amdgcn_cvt_pk_fp8_f32(v1.x * rn, v1.y * rn, 0, false);
        p1     = __builtin_amdgcn_cvt_pk_fp8_f32(v1.z * rn, v1.w * rn, p1, true);
        *(int2*)(dst + (size_t)r * D_DIM + lane * 8) = make_int2(p0, p1);
    }
}

struct TrueT  { static constexpr bool value = true;  };
struct FalseT { static constexpr bool value = false; };

// ---------------- GEMM (MX-fp8, identity scales) + softmax partials -----------
__global__ __launch_bounds__(256) void k_gemm(const uint8_t* __restrict__ embq,
                                              const uint8_t* __restrict__ wq,
                                              float* __restrict__ partials) {
    // LDS tile layout: 8 row-blocks of 16 rows; within block [kc 0..7][row 0..15]
    // 16B cells. global_load_lds lane order == layout order -> contiguous,
    // frag ds_read_b128: 16 consecutive lanes read 256 contiguous B (no conflict).
    __shared__ __align__(16) uint8_t A_s[128 * 128];
    __shared__ __align__(16) uint8_t B_s[128 * 128];
    __shared__ float Red[128][2];

    const int tid    = threadIdx.x;
    const int w      = tid >> 6;        // wave 0..3
    const int lane   = tid & 63;
    const int lanelo = lane & 15;
    const int quad   = lane >> 4;
    const int wrow0  = (w >> 1) * 64;   // wave's row base in tile
    const int wcol0  = (w & 1) * 64;    // wave's col base in tile

    // XCD-affinity decode: round-robin dispatch -> xcd = id & 7 (heuristic).
    // XCD k owns chunks [k*49, k*49+48]; its B slice (3.1 MB) + A (1 MB) fit L2.
    const int id    = blockIdx.x;
    const int xcd   = id & 7;
    const int s     = id >> 3;          // 0..783
    const int rb_   = s & 15;           // row-block
    const int chunk = xcd * CPX + (s >> 4);
    if (chunk >= NCHUNK) return;        // 8 pad slots
    const int b0 = rb_ * 128;
    const int n0 = chunk * 128;

    const uint8_t* Abase = embq + (size_t)b0 * D_DIM;
    const uint8_t* Bbase = wq   + (size_t)n0 * D_DIM;

    f32x4 acc[4][4];
    #pragma unroll
    for (int i = 0; i < 4; ++i)
        #pragma unroll
        for (int j = 0; j < 4; ++j)
            acc[i][j] = (f32x4){0.f, 0.f, 0.f, 0.f};

    const int srow = lane & 15;
    const int skc  = lane >> 4;

    auto stage = [&](int kt) {
        const int k0 = kt * 128;
        #pragma unroll
        for (int t = 0; t < 2; ++t) {
            const int rb = w * 2 + t;           // 0..7 across waves
            #pragma unroll
            for (int h = 0; h < 2; ++h) {
                const int kc = h * 4 + skc;     // 0..7
                gload_lds16(Abase + (size_t)(rb * 16 + srow) * D_DIM + k0 + kc * 16,
                            &A_s[rb * 2048 + h * 1024]);
                gload_lds16(Bbase + (size_t)(rb * 16 + srow) * D_DIM + k0 + kc * 16,
                            &B_s[rb * 2048 + h * 1024]);
            }
        }
    };

    stage(0);
    #pragma unroll
    for (int kt = 0; kt < 4; ++kt) {
        __syncthreads();                 // drain vmcnt -> tile kt resident

        i32x8 af[4], bfr[4];             // pull frags to regs (ds_read_b128 x2)
        #pragma unroll
        for (int i = 0; i < 4; ++i) {
            const int rb = (w >> 1) * 4 + i;
            i32x4 lo = *(const i32x4*)&A_s[rb * 2048 + quad * 512 + lanelo * 16];
            i32x4 hi = *(const i32x4*)&A_s[rb * 2048 + quad * 512 + 256 + lanelo * 16];
            af[i] = (i32x8){lo[0], lo[1], lo[2], lo[3], hi[0], hi[1], hi[2], hi[3]};
        }
        #pragma unroll
        for (int j = 0; j < 4; ++j) {
            const int rb = (w & 1) * 4 + j;
            i32x4 lo = *(const i32x4*)&B_s[rb * 2048 + quad * 512 + lanelo * 16];
            i32x4 hi = *(const i32x4*)&B_s[rb * 2048 + quad * 512 + 256 + lanelo * 16];
            bfr[j] = (i32x8){lo[0], lo[1], lo[2], lo[3], hi[0], hi[1], hi[2], hi[3]};
        }
        __syncthreads();                 // all frags in regs -> LDS reusable

        if (kt < 3) stage(kt + 1);       // staging flies under the mfma burst

        #pragma unroll
        for (int i = 0; i < 4; ++i)
            #pragma unroll
            for (int j = 0; j < 4; ++j)
                acc[i][j] = __builtin_amdgcn_mfma_scale_f32_16x16x128_f8f6f4(
                    af[i], bfr[j], acc[i][j],
                    0, 0,          // cbsz=fp8(e4m3), blgp=fp8(e4m3)
                    0, 127,        // scale A: identity (E8M0 127 = 1.0)
                    0, 127);       // scale B: identity
    }

    // epilogue: C/D layout col=lane&15, row=quad*4+reg (shape-determined)
    auto epi = [&](auto maskTag) {
        constexpr bool MASK = decltype(maskTag)::value;
        #pragma unroll
        for (int i = 0; i < 4; ++i) {
            #pragma unroll
            for (int reg = 0; reg < 4; ++reg) {
                float s4 = 0.f;
                #pragma unroll
                for (int j = 0; j < 4; ++j) {
                    float t = __builtin_amdgcn_exp2f(
                        fmaf(acc[i][j][reg], K_LOG2E_S, -K_LOG2E_S));
                    if (MASK) {
                        int c = n0 + wcol0 + j * 16 + lanelo;
                        if (c >= C_CLASSES) t = 0.f;
                    }
                    s4 += t;
                }
                #pragma unroll
                for (int off = 1; off < 16; off <<= 1)
                    s4 += __shfl_xor(s4, off);
                if (lanelo == 0)
                    Red[wrow0 + i * 16 + quad * 4 + reg][w & 1] = s4;
            }
        }
    };
    if (chunk == NCHUNK - 1) epi(TrueT{}); else epi(FalseT{});
    __syncthreads();

    if (tid < 128)
        partials[(size_t)(b0 + tid) * NCHUNK + chunk] = Red[tid][0] + Red[tid][1];
}

// -------- finalize: exact label logit + partial sum -> atomic mean NLL --------
// 2 waves per row: role 0 = exact label dot, role 1 = partials sum.
// Block = 256 threads = 4 waves = 2 rows; grid = B/2 = 1024 blocks.
__global__ __launch_bounds__(256) void k_fin(const float* __restrict__ emb,
                                             const float* __restrict__ weight,
                                             const float* __restrict__ einv,
                                             const float* __restrict__ winv,
                                             const int* __restrict__ labels,
                                             const float* __restrict__ partials,
                                             float* __restrict__ out) {
    __shared__ float s_dot[2], s_ls[2];
    int widx = threadIdx.x >> 6;       // 0..3
    int lane = threadIdx.x & 63;
    int rloc = widx & 1;               // row within block
    int role = widx >> 1;              // 0 = dot, 1 = partials
    int b    = blockIdx.x * 2 + rloc;

    if (role == 0) {
        int label = labels[b];
        const float4* e  = (const float4*)(emb + (size_t)b * D_DIM);
        const float4* wt = (const float4*)(weight + (size_t)label * D_DIM);
        float4 e0 = e[lane],  e1 = e[lane + 64];
        float4 w0 = wt[lane], w1 = wt[lane + 64];
        float dot = e0.x*w0.x + e0.y*w0.y + e0.z*w0.z + e0.w*w0.w
                  + e1.x*w1.x + e1.y*w1.y + e1.z*w1.z + e1.w*w1.w;
        #pragma unroll
        for (int off = 32; off; off >>= 1) dot += __shfl_xor(dot, off);
        if (lane == 0) s_dot[rloc] = dot;
    } else {
        // 7 predicated loads, all issued before use; same add order as the
        // old strided loop (t ascending), so per-row fp result is identical.
        float p[7];
        #pragma unroll
        for (int t = 0; t < 7; ++t) {
            int idx = lane + t * 64;
            p[t] = (idx < NCHUNK) ? partials[(size_t)b * NCHUNK + idx] : 0.f;
        }
        float ls = p[0];
        #pragma unroll
        for (int t = 1; t < 7; ++t) ls += p[t];
        #pragma unroll
        for (int off = 32; off; off >>= 1) ls += __shfl_xor(ls, off);
        if (lane == 0) s_ls[rloc] = ls;
    }
    __syncthreads();

    if (threadIdx.x < 2) {
        int r = threadIdx.x;
        int b2 = blockIdx.x * 2 + r;
        int label = labels[b2];
        float cosv   = s_dot[r] * einv[b2] * winv[label];
        float l_orig = ARC_SCALE * cosv;
        float l_adj  = ARC_SCALE * (cosv - ARC_MARGIN);
        // swap (fp8-accumulated) label term for exact margin-adjusted one
        float s_adj = s_ls[r] - __expf(l_orig - ARC_SCALE) + __expf(l_adj - ARC_SCALE);
        float v = ARC_SCALE + logf(s_adj) - l_adj;
        atomicAdd(out, v * (1.0f / (float)B_ROWS));
    }
}

extern "C" void kernel_launch(void* const* d_in, const int* in_sizes, int n_in,
                              void* d_out, int out_size, void* d_ws, size_t ws_size,
                              hipStream_t stream) {
    const float* emb    = (const float*)d_in[0];   // (2048, 512) f32
    const int*   labels = (const int*)d_in[1];     // (2048,) i32 (jax x64 off)
    const float* weight = (const float*)d_in[2];   // (50000, 512) f32
    float* out = (float*)d_out;

    char* ws = (char*)d_ws;
    uint8_t* wq    = (uint8_t*)(ws + OFF_WQ);
    uint8_t* embq  = (uint8_t*)(ws + OFF_EMBQ);
    float* winv     = (float*)(ws + OFF_WINV);
    float* einv     = (float*)(ws + OFF_EINV);
    float* partials = (float*)(ws + OFF_PART);

    // (C_PAD + B_ROWS) rows, 4 rows/wave, 4 waves/block
    k_prep<<<(C_PAD + B_ROWS) / 16, 256, 0, stream>>>(emb, weight, embq, wq,
                                                      einv, winv, out);

    k_gemm<<<8 * CPX * 16, 256, 0, stream>>>(embq, wq, partials);

    k_fin<<<B_ROWS / 2, 256, 0, stream>>>(emb, weight, einv, winv, labels,
                                          partials, out);
}